// Round 9
// baseline (594.845 us; speedup 1.0000x reference)
//
#include <hip/hip_runtime.h>

// GraphNormalization on MI355X — R9: 4-task pipeline, write-hiding + depth.
//
// Model (R0-R8): reads service at ~3.3 TB/s chip-wide (copy=3.15R+3.15W,
// fill=6.5W, all read phases 3.1-3.4 across occupancy 23-76% and MLP 4-16KB);
// writes ~6.5 and overlap reads. Traffic minimal (FETCH 1.03GB, WRITE 1.03GB,
// re-reads L3-absorbed). Floor = read time ~310us iff writes hide under reads.
// R8 (depth-4 staging) = 489us: ~160us of writes still serialized.
// R9: 512 blocks x 4 tasks (node 2k, 2k+1, edge 2k, 2k+1).
//   ph0: stats(task0)            pure HBM read, depth-4 ring
//   ph1-3: stats(t) || write(t-1) fused, depth-2 per stream, counted vmcnt
//   ph4: write(task3)            depth-4 ring, store-aware vmcnt
// 3/4 of writes hide under reads -> model ~370-400us.

static constexpr int   D4     = 32;              // D/4, D = 128
static constexpr int   CHUNK  = 64;              // f4 per staging inst (1KB/wave)
static constexpr int   NCHUNK = 4;               // insts per wave-tile
static constexpr int   TILE_W = CHUNK * NCHUNK;  // 256 f4 = 4KB per wave
static constexpr int   TILE_B = TILE_W * 4;      // 1024 f4 per block-tile
static constexpr float EPS    = 1e-5f;

typedef float vfloat4 __attribute__((ext_vector_type(4)));

#define WAITV(N) do { asm volatile("s_waitcnt vmcnt(" #N ")" ::: "memory"); \
                      __builtin_amdgcn_sched_barrier(0); } while (0)

__device__ __forceinline__ void waitv_dyn(int n) {   // wave-uniform, mult of 4
    switch (n) {
        case 0:  WAITV(0);  break;
        case 4:  WAITV(4);  break;
        case 8:  WAITV(8);  break;
        case 12: WAITV(12); break;
        case 16: WAITV(16); break;
        case 20: WAITV(20); break;
        default: WAITV(24); break;
    }
}

__device__ __forceinline__ void nt_store4(float4* p, const float4& v) {
    vfloat4 w = { v.x, v.y, v.z, v.w };
    __builtin_nontemporal_store(w, reinterpret_cast<vfloat4*>(p));
}

__device__ __forceinline__ void acc4(float4& s, float4& q, const float4& v) {
    s.x += v.x; s.y += v.y; s.z += v.z; s.w += v.w;
    q.x += v.x * v.x; q.y += v.y * v.y;
    q.z += v.z * v.z; q.w += v.w * v.w;
}

__device__ __forceinline__ float4 affine4(const float4& v, const float4& A,
                                          const float4& Bc) {
    float4 o;
    o.x = v.x * A.x + Bc.x; o.y = v.y * A.y + Bc.y;
    o.z = v.z * A.z + Bc.z; o.w = v.w * A.w + Bc.w;
    return o;
}

__global__ __launch_bounds__(256) void seg_norm_k4(
    const float4* __restrict__ xn, const float4* __restrict__ xe,
    const float*  __restrict__ gn, const float*  __restrict__ bn,
    const float*  __restrict__ ge, const float*  __restrict__ be,
    const int*    __restrict__ sn, const int*    __restrict__ se,
    float4* __restrict__ on, float4* __restrict__ oe,
    int N)
{
    __shared__ float4 stage[4][4][TILE_W];      // 64 KB wave-private bufs
    __shared__ float4 redS[256], redQ[256];     // 8 KB
    __shared__ int    sb[8];

    const int k    = (int)blockIdx.x;           // 0..511
    const int tid  = (int)threadIdx.x;
    const int w    = tid >> 6;
    const int lane = tid & 63;
    const int dg   = tid & 31;

    // bounds for 4 tasks: t0=node 2k, t1=node 2k+1, t2=edge 2k, t3=edge 2k+1
    if (tid < 8) {
        const int t      = tid >> 1;
        const int* sg    = (t < 2) ? sn : se;
        const int target = 2 * k + (t & 1) + (tid & 1);
        int lo = 0, hi = N;
        while (lo < hi) {
            int mid = (lo + hi) >> 1;
            if (sg[mid] < target) lo = mid + 1; else hi = mid;
        }
        sb[tid] = lo;
    }
    __syncthreads();

    auto issue = [&](const float4* src, size_t fb, int t, float4* lp) {
        const float4* gp = src + fb + (size_t)t * TILE_B + w * TILE_W + lane;
        #pragma unroll
        for (int i = 0; i < NCHUNK; ++i)
            __builtin_amdgcn_global_load_lds(gp + i * CHUNK, lp + i * CHUNK, 16, 0, 0);
    };

    // carried write-stream state (set at end of each stats phase)
    const float4* wx = nullptr;  float4* wo = nullptr;
    size_t wfb = 0;  int wfc = 0, wnt = 0;
    float4 Aw = make_float4(0,0,0,0), Bw = make_float4(0,0,0,0);

    for (int ph = 0; ph <= 4; ++ph) {
        const bool hasS = (ph < 4), hasW = (ph > 0);

        const float4* sx = nullptr;
        size_t sfb = 0;  int sfc = 0, snt = 0, scnt = 0;
        if (hasS) {
            sx = (ph < 2) ? xn : xe;
            const int st = sb[2 * ph], en = sb[2 * ph + 1];
            scnt = en - st;
            sfb  = (size_t)st * D4;
            sfc  = scnt * D4;
            snt  = sfc / TILE_B;
        }

        float4 s = make_float4(0,0,0,0), q = make_float4(0,0,0,0);

        if (hasS && hasW) {
            // ---- fused: stats(ph) depth-2 || write(ph-1) depth-2 ----
            const int tmid = min(snt, wnt);
            if (tmid > 0) {
                issue(sx, sfb, 0, &stage[w][0][0]);
                issue(wx, wfb, 0, &stage[w][2][0]);
                if (tmid > 1) {
                    issue(sx, sfb, 1, &stage[w][1][0]);
                    issue(wx, wfb, 1, &stage[w][3][0]);
                }
                for (int t = 0; t < tmid; ++t) {
                    waitv_dyn(8 * min(1, tmid - 1 - t) + 4 * min(1, t));
                    float4* sc = &stage[w][t & 1][0];
                    float4* wc = &stage[w][2 + (t & 1)][0];
                    float4* op = wo + wfb + (size_t)t * TILE_B + w * TILE_W + lane;
                    #pragma unroll
                    for (int i = 0; i < NCHUNK; ++i) {
                        acc4(s, q, sc[i * CHUNK + lane]);
                        nt_store4(op + i * CHUNK,
                                  affine4(wc[i * CHUNK + lane], Aw, Bw));
                    }
                    if (t + 2 < tmid) {
                        issue(sx, sfb, t + 2, sc);
                        issue(wx, wfb, t + 2, wc);
                    }
                }
                WAITV(0);
            }
            for (int j = tmid * TILE_B + tid; j < sfc; j += 256)
                acc4(s, q, sx[sfb + j]);
            for (int j = tmid * TILE_B + tid; j < wfc; j += 256)
                nt_store4(&wo[wfb + j], affine4(wx[wfb + j], Aw, Bw));
        } else if (hasS) {
            // ---- ph0: pure stats, depth-4 ring ----
            if (snt > 0) {
                const int pre = min(snt, 4);
                for (int p = 0; p < pre; ++p) issue(sx, sfb, p, &stage[w][p][0]);
                for (int t = 0; t < snt; ++t) {
                    waitv_dyn(4 * min(3, snt - 1 - t));
                    float4* cur = &stage[w][t & 3][0];
                    #pragma unroll
                    for (int i = 0; i < NCHUNK; ++i)
                        acc4(s, q, cur[i * CHUNK + lane]);
                    if (t + 4 < snt) issue(sx, sfb, t + 4, cur);
                }
            }
            for (int j = snt * TILE_B + tid; j < sfc; j += 256)
                acc4(s, q, sx[sfb + j]);
        } else {
            // ---- ph4: pure write, depth-4 ring, store-aware vmcnt ----
            if (wnt > 0) {
                const int pre = min(wnt, 4);
                for (int p = 0; p < pre; ++p) issue(wx, wfb, p, &stage[w][p][0]);
                for (int t = 0; t < wnt; ++t) {
                    waitv_dyn(4 * min(3, wnt - 1 - t) + 4 * min(3, t));
                    float4* cur = &stage[w][t & 3][0];
                    float4* op  = wo + wfb + (size_t)t * TILE_B + w * TILE_W + lane;
                    #pragma unroll
                    for (int i = 0; i < NCHUNK; ++i)
                        nt_store4(op + i * CHUNK,
                                  affine4(cur[i * CHUNK + lane], Aw, Bw));
                    if (t + 4 < wnt) issue(wx, wfb, t + 4, cur);
                }
            }
            for (int j = wnt * TILE_B + tid; j < wfc; j += 256)
                nt_store4(&wo[wfb + j], affine4(wx[wfb + j], Aw, Bw));
        }

        if (hasS) {
            // ---- reduce + fold gamma/beta -> Aw/Bw for next phase ----
            __syncthreads();             // prior redS readers done
            redS[tid] = s; redQ[tid] = q;
            __syncthreads();
            if (tid < 32) {
                float4 S = redS[tid], Q = redQ[tid];
                #pragma unroll
                for (int j = 1; j < 8; ++j) {
                    const float4 a = redS[j * 32 + tid], c = redQ[j * 32 + tid];
                    S.x += a.x; S.y += a.y; S.z += a.z; S.w += a.w;
                    Q.x += c.x; Q.y += c.y; Q.z += c.z; Q.w += c.w;
                }
                const float rc = 1.0f / (float)max(scnt, 1);
                float4 m, iv;
                m.x = S.x * rc; m.y = S.y * rc; m.z = S.z * rc; m.w = S.w * rc;
                iv.x = 1.0f / (sqrtf(fmaxf(Q.x * rc - m.x * m.x, 0.f)) + EPS);
                iv.y = 1.0f / (sqrtf(fmaxf(Q.y * rc - m.y * m.y, 0.f)) + EPS);
                iv.z = 1.0f / (sqrtf(fmaxf(Q.z * rc - m.z * m.z, 0.f)) + EPS);
                iv.w = 1.0f / (sqrtf(fmaxf(Q.w * rc - m.w * m.w, 0.f)) + EPS);
                if (scnt <= 1) {         // pass-through: out = x*gamma + beta
                    m  = make_float4(0.f, 0.f, 0.f, 0.f);
                    iv = make_float4(1.f, 1.f, 1.f, 1.f);
                }
                const float* gm = (ph < 2) ? gn : ge;
                const float* bt = (ph < 2) ? bn : be;
                const float4 g4 = ((const float4*)gm)[tid];
                const float4 b4 = ((const float4*)bt)[tid];
                float4 A, Bc;
                A.x = iv.x * g4.x; A.y = iv.y * g4.y;
                A.z = iv.z * g4.z; A.w = iv.w * g4.w;
                Bc.x = b4.x - m.x * A.x; Bc.y = b4.y - m.y * A.y;
                Bc.z = b4.z - m.z * A.z; Bc.w = b4.w - m.w * A.w;
                redS[tid] = A; redQ[tid] = Bc;   // same-wave lanes only
            }
            __syncthreads();
            Aw = redS[dg]; Bw = redQ[dg];
            // next phase's write stream = this phase's stats stream
            wx = sx; wo = (ph < 2) ? on : oe;
            wfb = sfb; wfc = sfc; wnt = snt;
        }
    }
}

extern "C" void kernel_launch(void* const* d_in, const int* in_sizes, int n_in,
                              void* d_out, int out_size, void* d_ws, size_t ws_size,
                              hipStream_t stream) {
    const float* node_feat  = (const float*)d_in[0];
    const float* edge_feat  = (const float*)d_in[1];
    const float* node_gamma = (const float*)d_in[2];
    const float* node_beta  = (const float*)d_in[3];
    const float* edge_gamma = (const float*)d_in[4];
    const float* edge_beta  = (const float*)d_in[5];
    const int*   node_seg   = (const int*)d_in[6];
    const int*   edge_seg   = (const int*)d_in[7];

    const int D = in_sizes[2];        // 128
    const int N = in_sizes[0] / D;    // 1,000,000
    const int B = 1024;               // num_graphs (fixed by setup_inputs)

    float* out_node = (float*)d_out;
    float* out_edge = out_node + (size_t)N * (size_t)D;

    seg_norm_k4<<<dim3((unsigned)(B / 2)), 256, 0, stream>>>(
        (const float4*)node_feat, (const float4*)edge_feat,
        node_gamma, node_beta, edge_gamma, edge_beta,
        node_seg, edge_seg,
        (float4*)out_node, (float4*)out_edge, N);
}

// Round 10
// 594.817 us; speedup vs baseline: 1.0000x; 1.0000x over previous
//
#include <hip/hip_runtime.h>

// GraphNormalization on MI355X — R10: producer/consumer wave specialization.
//
// Model (R0-R9): HBM reads service at ~3.3 TB/s chip-wide in every structure
// (copy=3.15R+3.15W, fill=6.5W); writes ~6.5 and coexist with reads. Traffic
// is minimal (FETCH=1.03GB read-once, WRITE=1.03GB, re-reads L3-absorbed).
// R8 (489us) == serial read(311)+write(158): lockstep phases, no overlap.
// R9 failed because both streams shared one wave's in-order vmcnt.
// R10: separate streams into separate WAVES (independent vmcnt): per block
// (one per graph b), waves 0-1 stream stats-reads (node then edge, depth-4
// rings); waves 2-3 trail: fold stats, then staged L3 re-read + NT-store.
// Sync via LDS flags (acquire/release), no __syncthreads after start.

static constexpr int   D4     = 32;    // f4 per row (D=128)
static constexpr int   CHUNK  = 64;    // f4 per global_load_lds inst (1KB/wave)
static constexpr int   NCHUNK = 4;     // insts per wave-tile
static constexpr int   TILE_W = 256;   // f4 per wave-tile (4KB)
static constexpr int   DEPTH  = 4;     // ring depth per wave
static constexpr float EPS    = 1e-5f;

typedef float vfloat4 __attribute__((ext_vector_type(4)));

#define WAITV(N) do { asm volatile("s_waitcnt vmcnt(" #N ")" ::: "memory"); \
                      __builtin_amdgcn_sched_barrier(0); } while (0)

__device__ __forceinline__ void waitv_dyn(int n) {   // wave-uniform, mult of 4
    switch (n) {
        case 0:  WAITV(0);  break;
        case 4:  WAITV(4);  break;
        case 8:  WAITV(8);  break;
        case 12: WAITV(12); break;
        case 16: WAITV(16); break;
        case 20: WAITV(20); break;
        default: WAITV(24); break;
    }
}

__device__ __forceinline__ void nt_store4(float4* p, const float4& v) {
    vfloat4 w = { v.x, v.y, v.z, v.w };
    __builtin_nontemporal_store(w, reinterpret_cast<vfloat4*>(p));
}

__device__ __forceinline__ void acc4(float4& s, float4& q, const float4& v) {
    s.x += v.x; s.y += v.y; s.z += v.z; s.w += v.w;
    q.x += v.x * v.x; q.y += v.y * v.y;
    q.z += v.z * v.z; q.w += v.w * v.w;
}

__device__ __forceinline__ float4 affine4(const float4& v, const float4& A,
                                          const float4& Bc) {
    float4 o;
    o.x = v.x * A.x + Bc.x; o.y = v.y * A.y + Bc.y;
    o.z = v.z * A.z + Bc.z; o.w = v.w * A.w + Bc.w;
    return o;
}

__global__ __launch_bounds__(256) void seg_norm_pc(
    const float4* __restrict__ xn, const float4* __restrict__ xe,
    const float*  __restrict__ gn, const float*  __restrict__ bn,
    const float*  __restrict__ ge, const float*  __restrict__ be,
    const int*    __restrict__ sn, const int*    __restrict__ se,
    float4* __restrict__ on, float4* __restrict__ oe,
    int N)
{
    __shared__ float4 ring[4][DEPTH][TILE_W];   // 64 KB, one ring per wave
    __shared__ float4 pS[2][2][64], pQ[2][2][64];  // 8 KB reader partials
    __shared__ float4 sA[2][32], sBc[2][32];    // 2 KB folded scale/bias
    __shared__ int    sb[4];                    // node[st,en), edge[st,en)
    __shared__ int    flags[4];  // 0:nodeParts 1:nodeFold 2:edgeParts 3:edgeFold

    const int b    = (int)blockIdx.x;
    const int tid  = (int)threadIdx.x;
    const int w    = tid >> 6;      // wave 0..3
    const int lane = tid & 63;
    const int dg   = lane & 31;     // dim-group

    if (tid < 4) {
        const int* sg    = (tid < 2) ? sn : se;
        const int target = b + (tid & 1);
        int lo = 0, hi = N;
        while (lo < hi) {
            int mid = (lo + hi) >> 1;
            if (sg[mid] < target) lo = mid + 1; else hi = mid;
        }
        sb[tid] = lo;
        flags[tid] = 0;
    }
    __syncthreads();   // only block-wide barrier; before any divergence

    auto issue = [&](const float4* src, size_t fb, int t, float4* lp) {
        const float4* gp = src + fb + (size_t)t * TILE_W + lane;
        #pragma unroll
        for (int i = 0; i < NCHUNK; ++i)
            __builtin_amdgcn_global_load_lds(gp + i * CHUNK, lp + i * CHUNK, 16, 0, 0);
    };

    if (w < 2) {
        // =================== READER waves 0-1 ===========================
        for (int seg = 0; seg < 2; ++seg) {
            const float4* src = seg ? xe : xn;
            const int st = sb[seg * 2], en = sb[seg * 2 + 1];
            const size_t fb = (size_t)st * D4;
            const int fc = (en - st) * D4;
            const int nt = fc / TILE_W;
            const int myCnt = (nt + 1 - w) / 2;      // tiles t = w + 2j
            float4 s = make_float4(0,0,0,0), q = make_float4(0,0,0,0);
            const int pre = min(myCnt, DEPTH);
            for (int p = 0; p < pre; ++p)
                issue(src, fb, w + 2 * p, &ring[w][p][0]);
            for (int j = 0; j < myCnt; ++j) {
                waitv_dyn(4 * min(3, myCnt - 1 - j));
                float4* cur = &ring[w][j & 3][0];
                #pragma unroll
                for (int i = 0; i < NCHUNK; ++i)
                    acc4(s, q, cur[i * CHUNK + lane]);
                if (j + DEPTH < myCnt) issue(src, fb, w + 2 * (j + DEPTH), cur);
            }
            if (w == 0) {   // tail rows (fc always multiple of 32)
                for (int j2 = nt * TILE_W + lane; j2 < fc; j2 += 64)
                    acc4(s, q, src[fb + j2]);
            }
            pS[seg][w][lane] = s; pQ[seg][w][lane] = q;
            __threadfence_block();
            if (lane == 0)
                __hip_atomic_fetch_add(&flags[seg * 2], 1,
                                       __ATOMIC_RELEASE, __HIP_MEMORY_SCOPE_WORKGROUP);
        }
    } else {
        // =================== WRITER waves 2-3 ===========================
        for (int seg = 0; seg < 2; ++seg) {
            const float4* src = seg ? xe : xn;
            float4*       dst = seg ? oe : on;
            const float*  gm  = seg ? ge : gn;
            const float*  bt  = seg ? be : bn;
            const int st = sb[seg * 2], en = sb[seg * 2 + 1];
            const int scnt = en - st;
            const size_t fb = (size_t)st * D4;
            const int fc = scnt * D4;
            const int nt = fc / TILE_W;

            while (__hip_atomic_load(&flags[seg * 2], __ATOMIC_ACQUIRE,
                                     __HIP_MEMORY_SCOPE_WORKGROUP) < 2)
                __builtin_amdgcn_s_sleep(8);

            if (w == 2) {
                if (lane < 32) {
                    float4 S = pS[seg][0][lane], Q = pQ[seg][0][lane];
                    const float4 a1 = pS[seg][0][lane + 32], c1 = pQ[seg][0][lane + 32];
                    const float4 a2 = pS[seg][1][lane],      c2 = pQ[seg][1][lane];
                    const float4 a3 = pS[seg][1][lane + 32], c3 = pQ[seg][1][lane + 32];
                    S.x += a1.x + a2.x + a3.x; S.y += a1.y + a2.y + a3.y;
                    S.z += a1.z + a2.z + a3.z; S.w += a1.w + a2.w + a3.w;
                    Q.x += c1.x + c2.x + c3.x; Q.y += c1.y + c2.y + c3.y;
                    Q.z += c1.z + c2.z + c3.z; Q.w += c1.w + c2.w + c3.w;
                    const float rc = 1.0f / (float)max(scnt, 1);
                    float4 m, iv;
                    m.x = S.x * rc; m.y = S.y * rc; m.z = S.z * rc; m.w = S.w * rc;
                    iv.x = 1.0f / (sqrtf(fmaxf(Q.x * rc - m.x * m.x, 0.f)) + EPS);
                    iv.y = 1.0f / (sqrtf(fmaxf(Q.y * rc - m.y * m.y, 0.f)) + EPS);
                    iv.z = 1.0f / (sqrtf(fmaxf(Q.z * rc - m.z * m.z, 0.f)) + EPS);
                    iv.w = 1.0f / (sqrtf(fmaxf(Q.w * rc - m.w * m.w, 0.f)) + EPS);
                    if (scnt <= 1) {    // pass-through: out = x*gamma + beta
                        m  = make_float4(0.f, 0.f, 0.f, 0.f);
                        iv = make_float4(1.f, 1.f, 1.f, 1.f);
                    }
                    const float4 g4 = ((const float4*)gm)[lane];
                    const float4 b4 = ((const float4*)bt)[lane];
                    float4 A, Bc;
                    A.x = iv.x * g4.x; A.y = iv.y * g4.y;
                    A.z = iv.z * g4.z; A.w = iv.w * g4.w;
                    Bc.x = b4.x - m.x * A.x; Bc.y = b4.y - m.y * A.y;
                    Bc.z = b4.z - m.z * A.z; Bc.w = b4.w - m.w * A.w;
                    sA[seg][lane] = A; sBc[seg][lane] = Bc;
                }
                __threadfence_block();
                if (lane == 0)
                    __hip_atomic_store(&flags[seg * 2 + 1], 1,
                                       __ATOMIC_RELEASE, __HIP_MEMORY_SCOPE_WORKGROUP);
            } else {
                while (__hip_atomic_load(&flags[seg * 2 + 1], __ATOMIC_ACQUIRE,
                                         __HIP_MEMORY_SCOPE_WORKGROUP) < 1)
                    __builtin_amdgcn_s_sleep(8);
            }
            const float4 A  = sA[seg][dg];
            const float4 Bc = sBc[seg][dg];

            const int wv = w - 2;
            const int myCnt = (nt + 1 - wv) / 2;     // tiles t = wv + 2j
            const int pre = min(myCnt, DEPTH);
            for (int p = 0; p < pre; ++p)
                issue(src, fb, wv + 2 * p, &ring[w][p][0]);
            for (int j = 0; j < myCnt; ++j) {
                waitv_dyn(4 * min(3, myCnt - 1 - j) + 4 * min(3, j));
                float4* cur = &ring[w][j & 3][0];
                const int t = wv + 2 * j;
                float4* op = dst + fb + (size_t)t * TILE_W + lane;
                #pragma unroll
                for (int i = 0; i < NCHUNK; ++i)
                    nt_store4(op + i * CHUNK, affine4(cur[i * CHUNK + lane], A, Bc));
                if (j + DEPTH < myCnt) issue(src, fb, wv + 2 * (j + DEPTH), cur);
            }
            if (w == 2) {   // tail
                for (int j2 = nt * TILE_W + lane; j2 < fc; j2 += 64) {
                    const float4 Av = sA[seg][j2 & 31], Bv = sBc[seg][j2 & 31];
                    nt_store4(&dst[fb + j2], affine4(src[fb + j2], Av, Bv));
                }
            }
        }
    }
}

extern "C" void kernel_launch(void* const* d_in, const int* in_sizes, int n_in,
                              void* d_out, int out_size, void* d_ws, size_t ws_size,
                              hipStream_t stream) {
    const float* node_feat  = (const float*)d_in[0];
    const float* edge_feat  = (const float*)d_in[1];
    const float* node_gamma = (const float*)d_in[2];
    const float* node_beta  = (const float*)d_in[3];
    const float* edge_gamma = (const float*)d_in[4];
    const float* edge_beta  = (const float*)d_in[5];
    const int*   node_seg   = (const int*)d_in[6];
    const int*   edge_seg   = (const int*)d_in[7];

    const int D = in_sizes[2];        // 128
    const int N = in_sizes[0] / D;    // 1,000,000
    const int B = 1024;               // num_graphs (fixed by setup_inputs)

    float* out_node = (float*)d_out;
    float* out_edge = out_node + (size_t)N * (size_t)D;

    seg_norm_pc<<<dim3((unsigned)B), 256, 0, stream>>>(
        (const float4*)node_feat, (const float4*)edge_feat,
        node_gamma, node_beta, edge_gamma, edge_beta,
        node_seg, edge_seg,
        (float4*)out_node, (float4*)out_edge, N);
}

// Round 11
// 566.547 us; speedup vs baseline: 1.0499x; 1.0499x over previous
//
#include <hip/hip_runtime.h>

// GraphNormalization on MI355X — R11: R8 skeleton, 3 blocks/CU.
//
// Model (R0-R10): read phases pin at ~3.3 TB/s regardless of MLP (40-128
// KB/CU in flight) and occupancy (19-76%); write phase reaches ~5.8-6.5
// TB/s; all three attempts to overlap the streams (fused single-wave R7,
// shared-vmcnt R9, wave-specialized R10) regressed vs cleanly serialized
// phases. Serial-phase bound: 311us (read) + ~160us (write) ~= 470us.
// R8 = 489. R11 polish: DEPTH 4->3 + wave-shuffle pre-reduction shrinks
// LDS 74->52KB -> 3 blocks/CU (12 waves) for better write-phase TLP and
// smoother tails. Traffic stays 1.03GB R + 1.03GB W.

static constexpr int   D4     = 32;              // D/4, D = 128
static constexpr int   CHUNK  = 64;              // f4 per staging inst (1KB/wave)
static constexpr int   NCHUNK = 4;               // insts per wave-tile
static constexpr int   TILE_W = CHUNK * NCHUNK;  // 256 f4 = 4KB per wave
static constexpr int   TILE_B = TILE_W * 4;      // 1024 f4 per block-tile
static constexpr int   DEPTH  = 3;               // tiles in ring per wave
static constexpr float EPS    = 1e-5f;

typedef float vfloat4 __attribute__((ext_vector_type(4)));

#define WAITV(N) do { asm volatile("s_waitcnt vmcnt(" #N ")" ::: "memory"); \
                      __builtin_amdgcn_sched_barrier(0); } while (0)

__device__ __forceinline__ void waitv_dyn(int n) {   // wave-uniform, mult of 4
    switch (n) {
        case 0:  WAITV(0);  break;
        case 4:  WAITV(4);  break;
        case 8:  WAITV(8);  break;
        case 12: WAITV(12); break;
        default: WAITV(16); break;
    }
}

__device__ __forceinline__ void nt_store4(float4* p, const float4& v) {
    vfloat4 w = { v.x, v.y, v.z, v.w };
    __builtin_nontemporal_store(w, reinterpret_cast<vfloat4*>(p));
}

__device__ __forceinline__ void acc4(float4& s, float4& q, const float4& v) {
    s.x += v.x; s.y += v.y; s.z += v.z; s.w += v.w;
    q.x += v.x * v.x; q.y += v.y * v.y;
    q.z += v.z * v.z; q.w += v.w * v.w;
}

__device__ __forceinline__ float4 affine4(const float4& v, const float4& A,
                                          const float4& Bc) {
    float4 o;
    o.x = v.x * A.x + Bc.x; o.y = v.y * A.y + Bc.y;
    o.z = v.z * A.z + Bc.z; o.w = v.w * A.w + Bc.w;
    return o;
}

__global__ __launch_bounds__(256) void seg_norm_r11(
    const float4* __restrict__ xn, const float4* __restrict__ xe,
    const float*  __restrict__ gn, const float*  __restrict__ bn,
    const float*  __restrict__ ge, const float*  __restrict__ be,
    const int*    __restrict__ sn, const int*    __restrict__ se,
    float4* __restrict__ on, float4* __restrict__ oe,
    int N)
{
    __shared__ float4 ring[4][DEPTH][TILE_W];   // 48 KB wave-private rings
    __shared__ float4 pS[4][32], pQ[4][32];     // 4 KB wave partials / A,Bc
    __shared__ int    s_bounds[2];

    const bool is_edge = (blockIdx.y != 0);
    const float4* __restrict__ x   = is_edge ? xe : xn;
    const float*  __restrict__ gam = is_edge ? ge : gn;
    const float*  __restrict__ bet = is_edge ? be : bn;
    const int*    __restrict__ seg = is_edge ? se : sn;
    float4*       __restrict__ out = is_edge ? oe : on;

    const int b   = (int)blockIdx.x;
    const int tid = (int)threadIdx.x;

    if (tid < 2) {
        const int target = b + tid;
        int lo = 0, hi = N;
        while (lo < hi) {
            int mid = (lo + hi) >> 1;
            if (seg[mid] < target) lo = mid + 1; else hi = mid;
        }
        s_bounds[tid] = lo;
    }
    __syncthreads();
    const int start = s_bounds[0];
    const int end   = s_bounds[1];
    const int cnt   = end - start;
    if (cnt <= 0) return;

    const int w    = tid >> 6;    // wave 0..3
    const int lane = tid & 63;
    const int dg   = lane & 31;   // dim-group (4 dims per group)

    const size_t f4base = (size_t)start * D4;
    const int    f4cnt  = cnt * D4;
    const int    nt     = f4cnt / TILE_B;

    auto issue = [&](int t, float4* lp) {
        const float4* gp = x + f4base + (size_t)t * TILE_B + w * TILE_W + lane;
        #pragma unroll
        for (int i = 0; i < NCHUNK; ++i)
            __builtin_amdgcn_global_load_lds(gp + i * CHUNK, lp + i * CHUNK, 16, 0, 0);
    };

    // ---------------- pass A: stats, DEPTH-3 ring ---------------------------
    float4 s = make_float4(0.f, 0.f, 0.f, 0.f);
    float4 q = make_float4(0.f, 0.f, 0.f, 0.f);
    if (nt > 0) {
        const int pre = min(nt, DEPTH);
        for (int p = 0; p < pre; ++p) issue(p, &ring[w][p][0]);
        for (int t = 0; t < nt; ++t) {
            waitv_dyn(4 * min(DEPTH - 1, nt - 1 - t));
            float4* cur = &ring[w][t % DEPTH][0];
            #pragma unroll
            for (int i = 0; i < NCHUNK; ++i)
                acc4(s, q, cur[i * CHUNK + lane]);
            if (t + DEPTH < nt) issue(t + DEPTH, cur);
        }
    }
    for (int j = nt * TILE_B + tid; j < f4cnt; j += 256)
        acc4(s, q, x[f4base + j]);

    // ---------------- fold: in-wave shuffle + cross-wave LDS ----------------
    // lanes l and l+32 accumulate the same dim-group -> fold halves in-wave.
    s.x += __shfl_down(s.x, 32); s.y += __shfl_down(s.y, 32);
    s.z += __shfl_down(s.z, 32); s.w += __shfl_down(s.w, 32);
    q.x += __shfl_down(q.x, 32); q.y += __shfl_down(q.y, 32);
    q.z += __shfl_down(q.z, 32); q.w += __shfl_down(q.w, 32);
    if (lane < 32) { pS[w][lane] = s; pQ[w][lane] = q; }
    __syncthreads();
    if (tid < 32) {
        float4 S = pS[0][tid], Q = pQ[0][tid];
        #pragma unroll
        for (int k = 1; k < 4; ++k) {
            const float4 a = pS[k][tid], c = pQ[k][tid];
            S.x += a.x; S.y += a.y; S.z += a.z; S.w += a.w;
            Q.x += c.x; Q.y += c.y; Q.z += c.z; Q.w += c.w;
        }
        const float rc = 1.0f / (float)cnt;
        float4 m, iv;
        m.x = S.x * rc; m.y = S.y * rc; m.z = S.z * rc; m.w = S.w * rc;
        iv.x = 1.0f / (sqrtf(fmaxf(Q.x * rc - m.x * m.x, 0.f)) + EPS);
        iv.y = 1.0f / (sqrtf(fmaxf(Q.y * rc - m.y * m.y, 0.f)) + EPS);
        iv.z = 1.0f / (sqrtf(fmaxf(Q.z * rc - m.z * m.z, 0.f)) + EPS);
        iv.w = 1.0f / (sqrtf(fmaxf(Q.w * rc - m.w * m.w, 0.f)) + EPS);
        if (cnt <= 1) {  // pass-through: out = x*gamma + beta
            m  = make_float4(0.f, 0.f, 0.f, 0.f);
            iv = make_float4(1.f, 1.f, 1.f, 1.f);
        }
        const float4 g4 = ((const float4*)gam)[tid];
        const float4 b4 = ((const float4*)bet)[tid];
        float4 A, Bc;
        A.x = iv.x * g4.x; A.y = iv.y * g4.y; A.z = iv.z * g4.z; A.w = iv.w * g4.w;
        Bc.x = b4.x - m.x * A.x; Bc.y = b4.y - m.y * A.y;
        Bc.z = b4.z - m.z * A.z; Bc.w = b4.w - m.w * A.w;
        pS[0][tid] = A; pQ[0][tid] = Bc;    // same-wave lanes only: safe
    }
    __syncthreads();
    const float4 A  = pS[0][dg];
    const float4 Bc = pQ[0][dg];
    // pS/pQ are not written again; rings are wave-private -> no extra barrier.

    // ------- pass B: staged re-read (L2/L3) -> fma -> NT store, depth-3 ----
    if (nt > 0) {
        const int pre = min(nt, DEPTH);
        for (int p = 0; p < pre; ++p) issue(p, &ring[w][p][0]);
        for (int t = 0; t < nt; ++t) {
            // newer-than-tile-t VMEM ops (in-order retirement):
            //   loads of tiles t+1..t+DEPTH-1 + stores of iters t-DEPTH+1..t-1
            waitv_dyn(4 * min(DEPTH - 1, nt - 1 - t) + 4 * min(DEPTH - 1, t));
            float4* cur = &ring[w][t % DEPTH][0];
            float4* op  = out + f4base + (size_t)t * TILE_B + w * TILE_W + lane;
            #pragma unroll
            for (int i = 0; i < NCHUNK; ++i)
                nt_store4(op + i * CHUNK, affine4(cur[i * CHUNK + lane], A, Bc));
            if (t + DEPTH < nt) issue(t + DEPTH, cur);
        }
    }
    for (int j = nt * TILE_B + tid; j < f4cnt; j += 256)
        nt_store4(&out[f4base + j], affine4(x[f4base + j], A, Bc));
}

extern "C" void kernel_launch(void* const* d_in, const int* in_sizes, int n_in,
                              void* d_out, int out_size, void* d_ws, size_t ws_size,
                              hipStream_t stream) {
    const float* node_feat  = (const float*)d_in[0];
    const float* edge_feat  = (const float*)d_in[1];
    const float* node_gamma = (const float*)d_in[2];
    const float* node_beta  = (const float*)d_in[3];
    const float* edge_gamma = (const float*)d_in[4];
    const float* edge_beta  = (const float*)d_in[5];
    const int*   node_seg   = (const int*)d_in[6];
    const int*   edge_seg   = (const int*)d_in[7];

    const int D = in_sizes[2];        // 128
    const int N = in_sizes[0] / D;    // 1,000,000
    const int B = 1024;               // num_graphs (fixed by setup_inputs)

    float* out_node = (float*)d_out;
    float* out_edge = out_node + (size_t)N * (size_t)D;

    dim3 grid((unsigned)B, 2);
    seg_norm_r11<<<grid, 256, 0, stream>>>(
        (const float4*)node_feat, (const float4*)edge_feat,
        node_gamma, node_beta, edge_gamma, edge_beta,
        node_seg, edge_seg,
        (float4*)out_node, (float4*)out_edge, N);
}